// Round 5
// baseline (311.389 us; speedup 1.0000x reference)
//
#include <hip/hip_runtime.h>
#include <hip/hip_bf16.h>
#include <math.h>

#define HEADS 4
#define HID 32
#define FDIM 128   // HEADS*HID == IN
#define OUTC 10
#define NEG 0.2f

typedef __attribute__((ext_vector_type(4))) float f32x4;
typedef __attribute__((ext_vector_type(8))) short bf16x8;

static __device__ __forceinline__ float lrelu(float v) { return v > 0.f ? v : NEG * v; }

// round-to-nearest-even f32 -> bf16 (returns low 16 bits)
static __device__ __forceinline__ unsigned bfr(float f) {
  unsigned u = __float_as_uint(f);
  return (u + 0x7fffu + ((u >> 16) & 1u)) >> 16;
}
static __device__ __forceinline__ float blo(unsigned u) { return __uint_as_float(u << 16); }
static __device__ __forceinline__ float bhi(unsigned u) { return __uint_as_float(u & 0xffff0000u); }

// ---------------- CSR build ----------------
__global__ void k_count(const int* __restrict__ ei, int* __restrict__ deg, int E, int n) {
  int e = blockIdx.x * 256 + threadIdx.x;
  int tot = E + n;
  if (e >= tot) return;
  int dst = (e < E) ? ei[E + e] : (e - E);
  atomicAdd(&deg[dst], 1);
}

__global__ void k_scan_block(const int* __restrict__ deg, int* __restrict__ offs,
                             int* __restrict__ parts, int n) {
  __shared__ int sh[256];
  int i = blockIdx.x * 256 + threadIdx.x;
  int v = (i < n) ? deg[i] : 0;
  sh[threadIdx.x] = v;
  __syncthreads();
  #pragma unroll
  for (int off = 1; off < 256; off <<= 1) {
    int t = (threadIdx.x >= off) ? sh[threadIdx.x - off] : 0;
    __syncthreads();
    sh[threadIdx.x] += t;
    __syncthreads();
  }
  if (i < n) offs[i + 1] = sh[threadIdx.x];
  if (threadIdx.x == 255) parts[blockIdx.x] = sh[255];
}

__global__ void k_scan_parts(int* __restrict__ parts, int nb) {
  __shared__ int sh[256];
  int v = (threadIdx.x < nb) ? parts[threadIdx.x] : 0;
  sh[threadIdx.x] = v;
  __syncthreads();
  #pragma unroll
  for (int off = 1; off < 256; off <<= 1) {
    int t = (threadIdx.x >= off) ? sh[threadIdx.x - off] : 0;
    __syncthreads();
    sh[threadIdx.x] += t;
    __syncthreads();
  }
  if (threadIdx.x < nb) parts[threadIdx.x] = sh[threadIdx.x] - v;  // exclusive prefix
}

__global__ void k_add_offs(int* __restrict__ offs, const int* __restrict__ parts, int n) {
  int i = blockIdx.x * 256 + threadIdx.x;
  if (i < n) offs[i + 1] += parts[blockIdx.x];
  if (i == 0) offs[0] = 0;
}

// dst-range partitioned fill: pass handles dst in [lo,hi) so the written csr
// region (~850KB for 4 passes) stays L2-resident -> lines fully packed before
// writeback (cuts the 8-XCD write amplification / churn).
__global__ void k_fill_part(const int* __restrict__ ei, const int* __restrict__ offs,
                            int* __restrict__ cursor, int* __restrict__ csr,
                            int E, int n, int lo, int hi) {
  int e = blockIdx.x * 256 + threadIdx.x;
  int tot = E + n;
  if (e >= tot) return;
  int dst = (e < E) ? ei[E + e] : (e - E);
  if (dst < lo || dst >= hi) return;
  int src = (e < E) ? ei[e] : (e - E);
  int pos = atomicAdd(&cursor[dst], 1);
  csr[offs[dst] + pos] = src;
}

// ---------------- Wa = W @ [a_src; a_dst]^T  (128 x 8, f32) ----------------
__global__ void k_wa(const float* __restrict__ W, const float* __restrict__ as_,
                     const float* __restrict__ ad_, float* __restrict__ Wa) {
  int c = blockIdx.x;       // 0..7: 0-3 src heads, 4-7 dst heads
  int k = threadIdx.x;      // 0..127
  int h = c & 3;
  const float* av = (c < 4 ? as_ : ad_) + h * 32;
  const float* wr = W + (size_t)k * 128 + h * 32;
  float s = 0.f;
  #pragma unroll
  for (int j = 0; j < 32; j += 4) {
    float4 wv = *reinterpret_cast<const float4*>(wr + j);
    float4 a4 = *reinterpret_cast<const float4*>(av + j);
    s += wv.x * a4.x + wv.y * a4.y + wv.z * a4.z + wv.w * a4.w;
  }
  Wa[k * 8 + c] = s;
}

// ---------------- weight prep: pack W + Wa into B-fragment layout ----------
__global__ void k_prep(const float* __restrict__ W, const float* __restrict__ Wa,
                       uint4* __restrict__ WF) {
  int gid = blockIdx.x * 256 + threadIdx.x;  // 9*256 = 2304 = 36 frags * 64 lanes
  if (gid >= 2304) return;
  int lane = gid & 63, frag = gid >> 6;
  int t = frag / 9, ct = frag - t * 9;
  int quad = lane >> 4, r = lane & 15;
  int kbase = t * 32 + quad * 8;
  unsigned v[8];
  if (ct < 8) {
    int col = ct * 16 + r;
    #pragma unroll
    for (int j = 0; j < 8; ++j) v[j] = bfr(W[(size_t)(kbase + j) * 128 + col]);
  } else if (r < 8) {
    #pragma unroll
    for (int j = 0; j < 8; ++j) v[j] = bfr(Wa[(kbase + j) * 8 + r]);
  } else {
    #pragma unroll
    for (int j = 0; j < 8; ++j) v[j] = 0;
  }
  uint4 pk;
  pk.x = v[0] | (v[1] << 16);
  pk.y = v[2] | (v[3] << 16);
  pk.z = v[4] | (v[5] << 16);
  pk.w = v[6] | (v[7] << 16);
  WF[gid] = pk;
}

// ---------------- MFMA GEMM + attention logits ----------------
__global__ __launch_bounds__(256) void k_mm(
    const float* __restrict__ X, const uint4* __restrict__ WF,
    unsigned short* __restrict__ H, float* __restrict__ AL, int n) {
  __shared__ uint4 wf[2304];
  int tid = threadIdx.x;
  #pragma unroll
  for (int i = 0; i < 9; ++i) wf[i * 256 + tid] = WF[i * 256 + tid];
  __syncthreads();
  int lane = tid & 63, wid = tid >> 6;
  int quad = lane >> 4, r = lane & 15;
  int rowbase = blockIdx.x * 64 + wid * 16;
  int arow = rowbase + r;
  int arowc = arow < n ? arow : 0;
  const float* xp = X + (size_t)arowc * 128 + quad * 8;
  const bf16x8* wfs = (const bf16x8*)wf;

  f32x4 acc[9];
  #pragma unroll
  for (int ct = 0; ct < 9; ++ct) acc[ct] = 0;

  #pragma unroll
  for (int t = 0; t < 4; ++t) {
    float4 x0 = *reinterpret_cast<const float4*>(xp + t * 32);
    float4 x1 = *reinterpret_cast<const float4*>(xp + t * 32 + 4);
    bf16x8 a;
    a[0] = (short)bfr(x0.x); a[1] = (short)bfr(x0.y);
    a[2] = (short)bfr(x0.z); a[3] = (short)bfr(x0.w);
    a[4] = (short)bfr(x1.x); a[5] = (short)bfr(x1.y);
    a[6] = (short)bfr(x1.z); a[7] = (short)bfr(x1.w);
    #pragma unroll
    for (int ct = 0; ct < 9; ++ct)
      acc[ct] = __builtin_amdgcn_mfma_f32_16x16x32_bf16(
          a, wfs[(t * 9 + ct) * 64 + lane], acc[ct], 0, 0, 0);
  }

  int orow0 = rowbase + quad * 4;
  #pragma unroll
  for (int rr = 0; rr < 4; ++rr) {
    int orow = orow0 + rr;
    if (orow < n) {
      unsigned short* hp = H + (size_t)orow * 128 + r;
      #pragma unroll
      for (int ct = 0; ct < 8; ++ct) hp[ct * 16] = (unsigned short)bfr(acc[ct][rr]);
      if (r < 8) AL[(size_t)orow * 8 + r] = acc[8][rr];
    }
  }
}

// ---------------- per-dst softmax + aggregation ----------------
// One node per 16-lane group (4 nodes/wave, 16/block). Per 16-edge round:
// p = exp(e) edge-parallel (no max shift: logits O(1), f32 can't overflow),
// stage (p,src) in group-private LDS, then gather: each lane owns 8 features
// (one uint4 of bf16) and iterates ALL its group's edges -> no acc combine.
// z reduced with 4 shfl_xor within the group.
template<bool ELU_OUT>
__global__ __launch_bounds__(256) void k_agg(
    const unsigned short* __restrict__ H, const float* __restrict__ AL,
    const int* __restrict__ offs, const int* __restrict__ csr,
    const float* __restrict__ bias, float* __restrict__ OUT, int n) {
  __shared__ int s_l[16][16];
  __shared__ float p_l[16][16][4];
  int tid = threadIdx.x;
  int lane = tid & 63;
  int wid = tid >> 6;
  int r = lane & 15;
  int gg = wid * 4 + (lane >> 4);     // group id within block (0..15)
  int node = blockIdx.x * 16 + gg;
  bool nvalid = node < n;
  int nodec = nvalid ? node : 0;
  int beg = offs[nodec];
  int end = nvalid ? offs[nodec + 1] : beg;
  float4 adv = *reinterpret_cast<const float4*>(AL + (size_t)nodec * 8 + 4);
  int hsel = r >> 2;
  const uint4* hb = reinterpret_cast<const uint4*>(H) + r;

  float z0 = 0.f, z1 = 0.f, z2 = 0.f, z3 = 0.f;
  float acc[8];
  #pragma unroll
  for (int k = 0; k < 8; ++k) acc[k] = 0.f;

  for (int cb = beg; cb < end; cb += 16) {
    int idx = cb + r;
    bool v = idx < end;
    int s = 0;
    float p0 = 0.f, p1 = 0.f, p2 = 0.f, p3 = 0.f;
    if (v) {
      s = csr[idx];
      float4 a = *reinterpret_cast<const float4*>(AL + (size_t)s * 8);
      p0 = __expf(lrelu(a.x + adv.x));
      p1 = __expf(lrelu(a.y + adv.y));
      p2 = __expf(lrelu(a.z + adv.z));
      p3 = __expf(lrelu(a.w + adv.w));
    }
    z0 += p0; z1 += p1; z2 += p2; z3 += p3;

    s_l[gg][r] = s;
    *reinterpret_cast<float4*>(&p_l[gg][r][0]) = make_float4(p0, p1, p2, p3);
    // wave-coherent LDS (groups live in one wave): no barrier needed

    int cnt = min(16, end - cb);
    int j = 0;
    for (; j + 2 <= cnt; j += 2) {
      int sA = s_l[gg][j], sB = s_l[gg][j + 1];
      float pA = p_l[gg][j][hsel], pB = p_l[gg][j + 1][hsel];
      uint4 uA = hb[(size_t)sA * 16];
      uint4 uB = hb[(size_t)sB * 16];
      acc[0] = fmaf(pA, blo(uA.x), acc[0]); acc[1] = fmaf(pA, bhi(uA.x), acc[1]);
      acc[2] = fmaf(pA, blo(uA.y), acc[2]); acc[3] = fmaf(pA, bhi(uA.y), acc[3]);
      acc[4] = fmaf(pA, blo(uA.z), acc[4]); acc[5] = fmaf(pA, bhi(uA.z), acc[5]);
      acc[6] = fmaf(pA, blo(uA.w), acc[6]); acc[7] = fmaf(pA, bhi(uA.w), acc[7]);
      acc[0] = fmaf(pB, blo(uB.x), acc[0]); acc[1] = fmaf(pB, bhi(uB.x), acc[1]);
      acc[2] = fmaf(pB, blo(uB.y), acc[2]); acc[3] = fmaf(pB, bhi(uB.y), acc[3]);
      acc[4] = fmaf(pB, blo(uB.z), acc[4]); acc[5] = fmaf(pB, bhi(uB.z), acc[5]);
      acc[6] = fmaf(pB, blo(uB.w), acc[6]); acc[7] = fmaf(pB, bhi(uB.w), acc[7]);
    }
    if (j < cnt) {
      int sA = s_l[gg][j];
      float pA = p_l[gg][j][hsel];
      uint4 uA = hb[(size_t)sA * 16];
      acc[0] = fmaf(pA, blo(uA.x), acc[0]); acc[1] = fmaf(pA, bhi(uA.x), acc[1]);
      acc[2] = fmaf(pA, blo(uA.y), acc[2]); acc[3] = fmaf(pA, bhi(uA.y), acc[3]);
      acc[4] = fmaf(pA, blo(uA.z), acc[4]); acc[5] = fmaf(pA, bhi(uA.z), acc[5]);
      acc[6] = fmaf(pA, blo(uA.w), acc[6]); acc[7] = fmaf(pA, bhi(uA.w), acc[7]);
    }
  }

  // z reduction within the 16-lane group
  #pragma unroll
  for (int off = 1; off < 16; off <<= 1) {
    z0 += __shfl_xor(z0, off);
    z1 += __shfl_xor(z1, off);
    z2 += __shfl_xor(z2, off);
    z3 += __shfl_xor(z3, off);
  }
  float zh = (hsel == 0) ? z0 : (hsel == 1) ? z1 : (hsel == 2) ? z2 : z3;
  float inv = 1.f / (zh + 1e-16f);
  int f0 = r * 8;
  float4 b0 = *reinterpret_cast<const float4*>(bias + f0);
  float4 b1 = *reinterpret_cast<const float4*>(bias + f0 + 4);
  float o[8];
  o[0] = acc[0] * inv + b0.x; o[1] = acc[1] * inv + b0.y;
  o[2] = acc[2] * inv + b0.z; o[3] = acc[3] * inv + b0.w;
  o[4] = acc[4] * inv + b1.x; o[5] = acc[5] * inv + b1.y;
  o[6] = acc[6] * inv + b1.z; o[7] = acc[7] * inv + b1.w;
  if (ELU_OUT) {
    #pragma unroll
    for (int k = 0; k < 8; ++k) o[k] = o[k] > 0.f ? o[k] : expm1f(o[k]);
  }
  if (nvalid) {
    float* op = OUT + (size_t)node * 128 + f0;
    *reinterpret_cast<float4*>(op) = make_float4(o[0], o[1], o[2], o[3]);
    *reinterpret_cast<float4*>(op + 4) = make_float4(o[4], o[5], o[6], o[7]);
  }
}

// ---------------- pooling (batch is sorted) ----------------
__global__ __launch_bounds__(256) void k_pool(
    const float* __restrict__ X, const int* __restrict__ batch,
    float* __restrict__ pooled, int* __restrict__ gcnt, int n) {
  int lane = threadIdx.x & 63;
  int w = blockIdx.x * 4 + (threadIdx.x >> 6);
  int a = w * 64;
  if (a >= n) return;
  int b = min(a + 64, n);
  float accA = 0.f, accB = 0.f;
  int gcur = batch[a];
  int cg = 0;
  int node = a;
  while (node < b) {
    if (node + 4 <= b && batch[node + 3] == gcur) {
      float sA0 = X[(size_t)(node + 0) * 128 + lane];
      float sB0 = X[(size_t)(node + 0) * 128 + lane + 64];
      float sA1 = X[(size_t)(node + 1) * 128 + lane];
      float sB1 = X[(size_t)(node + 1) * 128 + lane + 64];
      float sA2 = X[(size_t)(node + 2) * 128 + lane];
      float sB2 = X[(size_t)(node + 2) * 128 + lane + 64];
      float sA3 = X[(size_t)(node + 3) * 128 + lane];
      float sB3 = X[(size_t)(node + 3) * 128 + lane + 64];
      accA += (sA0 + sA1) + (sA2 + sA3);
      accB += (sB0 + sB1) + (sB2 + sB3);
      cg += 4; node += 4;
      continue;
    }
    int g = batch[node];
    if (g != gcur) {
      atomicAdd(&pooled[(size_t)gcur * 128 + lane], accA);
      atomicAdd(&pooled[(size_t)gcur * 128 + lane + 64], accB);
      if (lane == 0) atomicAdd(&gcnt[gcur], cg);
      accA = accB = 0.f; cg = 0; gcur = g;
    }
    accA += X[(size_t)node * 128 + lane];
    accB += X[(size_t)node * 128 + lane + 64];
    ++cg; ++node;
  }
  atomicAdd(&pooled[(size_t)gcur * 128 + lane], accA);
  atomicAdd(&pooled[(size_t)gcur * 128 + lane + 64], accB);
  if (lane == 0) atomicAdd(&gcnt[gcur], cg);
}

// ---------------- classifier head ----------------
__global__ void k_head(const float* __restrict__ pooled, const int* __restrict__ gcnt,
                       const float* __restrict__ Wl, const float* __restrict__ bl,
                       float* __restrict__ out) {
  int g = blockIdx.x;
  int lane = threadIdx.x;  // 64 threads
  float cnt = fmaxf((float)gcnt[g], 1.f);
  float pA = pooled[(size_t)g * 128 + lane] / cnt;
  float pB = pooled[(size_t)g * 128 + lane + 64] / cnt;
  float l[OUTC];
  #pragma unroll
  for (int o = 0; o < OUTC; ++o) {
    float s = pA * Wl[lane * OUTC + o] + pB * Wl[(lane + 64) * OUTC + o];
    #pragma unroll
    for (int off = 32; off; off >>= 1) s += __shfl_xor(s, off);
    l[o] = s + bl[o];
  }
  float mx = l[0];
  #pragma unroll
  for (int o = 1; o < OUTC; ++o) mx = fmaxf(mx, l[o]);
  float se = 0.f;
  #pragma unroll
  for (int o = 0; o < OUTC; ++o) { l[o] = __expf(l[o] - mx); se += l[o]; }
  if (lane == 0) {
    float inv = 1.f / se;
    #pragma unroll
    for (int o = 0; o < OUTC; ++o) out[g * OUTC + o] = l[o] * inv;
  }
}

extern "C" void kernel_launch(void* const* d_in, const int* in_sizes, int n_in,
                              void* d_out, int out_size, void* d_ws, size_t ws_size,
                              hipStream_t stream) {
  const float* x   = (const float*)d_in[0];
  const float* W1  = (const float*)d_in[1];
  const float* a1s = (const float*)d_in[2];
  const float* a1d = (const float*)d_in[3];
  const float* b1  = (const float*)d_in[4];
  const float* W2  = (const float*)d_in[5];
  const float* a2s = (const float*)d_in[6];
  const float* a2d = (const float*)d_in[7];
  const float* b2  = (const float*)d_in[8];
  const float* Wl  = (const float*)d_in[9];
  const float* bl  = (const float*)d_in[10];
  const int* ei    = (const int*)d_in[11];
  const int* batch = (const int*)d_in[12];
  const int N = in_sizes[12];
  const int E = in_sizes[11] / 2;
  const int G = out_size / OUTC;
  float* out = (float*)d_out;
  (void)n_in; (void)ws_size;

  char* w = (char*)d_ws;
  auto alloc = [&](size_t bytes) { char* p = w; w += (bytes + 255) & ~(size_t)255; return (void*)p; };
  unsigned short* H = (unsigned short*)alloc((size_t)N * FDIM * sizeof(unsigned short));
  float* ACT    = (float*)alloc((size_t)N * FDIM * sizeof(float));
  float* AL     = (float*)alloc((size_t)N * 8 * sizeof(float));
  uint4* WF1    = (uint4*)alloc(2304 * sizeof(uint4));
  uint4* WF2    = (uint4*)alloc(2304 * sizeof(uint4));
  float* Wa     = (float*)alloc(128 * 8 * sizeof(float));
  int*   offs   = (int*)alloc((size_t)(N + 1) * sizeof(int));
  int*   csr    = (int*)alloc((size_t)(E + N) * sizeof(int));
  int*   parts  = (int*)alloc(256 * sizeof(int));
  // zero-init region: deg, cur, gcnt, pooled contiguous -> one memset
  char* z0 = w;
  int*   deg    = (int*)alloc((size_t)N * sizeof(int));
  int*   cur    = (int*)alloc((size_t)N * sizeof(int));
  int*   gcnt   = (int*)alloc((size_t)G * sizeof(int));
  float* pooled = (float*)alloc((size_t)G * FDIM * sizeof(float));
  size_t zbytes = (size_t)(w - z0);
  hipMemsetAsync(z0, 0, zbytes, stream);

  // weight prep first (independent of CSR)
  k_wa<<<8, 128, 0, stream>>>(W1, a1s, a1d, Wa);
  k_prep<<<9, 256, 0, stream>>>(W1, Wa, WF1);
  k_wa<<<8, 128, 0, stream>>>(W2, a2s, a2d, Wa);
  k_prep<<<9, 256, 0, stream>>>(W2, Wa, WF2);

  int tot = E + N;
  int eb = (tot + 255) / 256;
  int nb = (N + 255) / 256;
  k_count<<<eb, 256, 0, stream>>>(ei, deg, E, N);
  k_scan_block<<<nb, 256, 0, stream>>>(deg, offs, parts, N);
  k_scan_parts<<<1, 256, 0, stream>>>(parts, nb);
  k_add_offs<<<nb, 256, 0, stream>>>(offs, parts, N);
  // 4 dst-range passes: written csr region per pass ~L2-resident
  {
    int step = (N + 3) / 4;
    for (int p = 0; p < 4; ++p) {
      int lo = p * step;
      int hi = min(N, lo + step);
      k_fill_part<<<eb, 256, 0, stream>>>(ei, offs, cur, csr, E, N, lo, hi);
    }
  }

  int gb = (N + 63) / 64;
  int ab = (N + 15) / 16;
  k_mm<<<gb, 256, 0, stream>>>(x, WF1, H, AL, N);
  k_agg<true><<<ab, 256, 0, stream>>>(H, AL, offs, csr, b1, ACT, N);
  k_mm<<<gb, 256, 0, stream>>>(ACT, WF2, H, AL, N);
  k_agg<false><<<ab, 256, 0, stream>>>(H, AL, offs, csr, b2, ACT, N);

  int pb = (N + 255) / 256;
  k_pool<<<pb, 256, 0, stream>>>(ACT, batch, pooled, gcnt, N);
  k_head<<<G, 64, 0, stream>>>(pooled, gcnt, Wl, bl, out);
}

// Round 6
// 252.754 us; speedup vs baseline: 1.2320x; 1.2320x over previous
//
#include <hip/hip_runtime.h>
#include <hip/hip_bf16.h>
#include <math.h>

#define HEADS 4
#define HID 32
#define FDIM 128   // HEADS*HID == IN
#define OUTC 10
#define NEG 0.2f

typedef __attribute__((ext_vector_type(4))) float f32x4;
typedef __attribute__((ext_vector_type(8))) short bf16x8;

static __device__ __forceinline__ float lrelu(float v) { return v > 0.f ? v : NEG * v; }

// round-to-nearest-even f32 -> bf16 (returns low 16 bits)
static __device__ __forceinline__ unsigned bfr(float f) {
  unsigned u = __float_as_uint(f);
  return (u + 0x7fffu + ((u >> 16) & 1u)) >> 16;
}
static __device__ __forceinline__ float blo(unsigned u) { return __uint_as_float(u << 16); }
static __device__ __forceinline__ float bhi(unsigned u) { return __uint_as_float(u & 0xffff0000u); }

// ================= bucketed CSR build =================
// Buckets of 256 consecutive dst ids. Each CSR region is written by exactly
// ONE workgroup (one XCD) -> cache lines fully packed before writeback.
// Global 50K scan eliminated: offs = bucket_base + in-bucket LDS scan.

#define CHUNK 4096  // edges per block in hist/bin passes

// per-block LDS bucket histogram -> one global atomicAdd per (block,bucket)
__global__ __launch_bounds__(256) void k_bhist(
    const int* __restrict__ ei, int* __restrict__ gbc, int E, int n, int nb) {
  __shared__ int h[256];
  h[threadIdx.x] = 0;
  __syncthreads();
  int base = blockIdx.x * CHUNK;
  int tot = E + n;
  #pragma unroll
  for (int r = 0; r < 16; ++r) {
    int e = base + r * 256 + threadIdx.x;
    if (e < tot) {
      int dst = (e < E) ? ei[E + e] : (e - E);
      atomicAdd(&h[dst >> 8], 1);
    }
  }
  __syncthreads();
  if (threadIdx.x < nb && h[threadIdx.x]) atomicAdd(&gbc[threadIdx.x], h[threadIdx.x]);
}

// scan nb bucket counts -> bbase[0..nb] (exclusive, bbase[nb]=tot), gbcur=bbase
__global__ void k_bscan(const int* __restrict__ gbc, int* __restrict__ bbase,
                        int* __restrict__ gbcur, int nb) {
  __shared__ int sh[256];
  int v = (threadIdx.x < nb) ? gbc[threadIdx.x] : 0;
  sh[threadIdx.x] = v;
  __syncthreads();
  #pragma unroll
  for (int off = 1; off < 256; off <<= 1) {
    int t = (threadIdx.x >= off) ? sh[threadIdx.x - off] : 0;
    __syncthreads();
    sh[threadIdx.x] += t;
    __syncthreads();
  }
  int excl = sh[threadIdx.x] - v;
  if (threadIdx.x <= nb) bbase[threadIdx.x] = excl;
  if (threadIdx.x < nb) gbcur[threadIdx.x] = excl;
}

// counting-sort edges into bucket-major (src,dst) pairs; each block's edges
// for a bucket form one contiguous run (~CHUNK/196 * 8B)
__global__ __launch_bounds__(256) void k_bin(
    const int* __restrict__ ei, int* __restrict__ gbcur,
    int2* __restrict__ bbuf, int E, int n) {
  __shared__ int h[256];
  __shared__ int cur[256];
  h[threadIdx.x] = 0;
  __syncthreads();
  int base = blockIdx.x * CHUNK;
  int tot = E + n;
  #pragma unroll
  for (int r = 0; r < 16; ++r) {
    int e = base + r * 256 + threadIdx.x;
    if (e < tot) {
      int dst = (e < E) ? ei[E + e] : (e - E);
      atomicAdd(&h[dst >> 8], 1);
    }
  }
  __syncthreads();
  if (h[threadIdx.x]) cur[threadIdx.x] = atomicAdd(&gbcur[threadIdx.x], h[threadIdx.x]);
  __syncthreads();
  #pragma unroll
  for (int r = 0; r < 16; ++r) {
    int e = base + r * 256 + threadIdx.x;
    if (e < tot) {
      int src = (e < E) ? ei[e] : (e - E);
      int dst = (e < E) ? ei[E + e] : (e - E);
      int pos = atomicAdd(&cur[dst >> 8], 1);
      bbuf[pos] = make_int2(src, dst);
    }
  }
}

// one block per bucket: LDS deg hist -> LDS scan -> offs write -> LDS-cursor
// fill of the bucket's private csr slice (all atomics in LDS)
__global__ __launch_bounds__(256) void k_build(
    const int2* __restrict__ bbuf, const int* __restrict__ bbase,
    int* __restrict__ offs, int* __restrict__ csr, int n, int nb) {
  __shared__ int deg[256];
  __shared__ int sc[256];
  __shared__ int cur[256];
  int b = blockIdx.x;
  int ebeg = bbase[b], eend = bbase[b + 1];
  deg[threadIdx.x] = 0;
  __syncthreads();
  for (int i = ebeg + threadIdx.x; i < eend; i += 256)
    atomicAdd(&deg[bbuf[i].y & 255], 1);
  __syncthreads();
  int v = deg[threadIdx.x];
  sc[threadIdx.x] = v;
  __syncthreads();
  #pragma unroll
  for (int off = 1; off < 256; off <<= 1) {
    int t = (threadIdx.x >= off) ? sc[threadIdx.x - off] : 0;
    __syncthreads();
    sc[threadIdx.x] += t;
    __syncthreads();
  }
  int excl = sc[threadIdx.x] - v;
  int dst0 = b * 256 + threadIdx.x;
  if (dst0 < n) offs[dst0] = ebeg + excl;
  if (b == 0 && threadIdx.x == 0) offs[n] = bbase[nb];
  cur[threadIdx.x] = ebeg + excl;
  __syncthreads();
  for (int i = ebeg + threadIdx.x; i < eend; i += 256) {
    int2 sd = bbuf[i];
    int pos = atomicAdd(&cur[sd.y & 255], 1);
    csr[pos] = sd.x;
  }
}

// ---------------- Wa = W @ [a_src; a_dst]^T  (128 x 8, f32) ----------------
__global__ void k_wa(const float* __restrict__ W, const float* __restrict__ as_,
                     const float* __restrict__ ad_, float* __restrict__ Wa) {
  int c = blockIdx.x;       // 0..7: 0-3 src heads, 4-7 dst heads
  int k = threadIdx.x;      // 0..127
  int h = c & 3;
  const float* av = (c < 4 ? as_ : ad_) + h * 32;
  const float* wr = W + (size_t)k * 128 + h * 32;
  float s = 0.f;
  #pragma unroll
  for (int j = 0; j < 32; j += 4) {
    float4 wv = *reinterpret_cast<const float4*>(wr + j);
    float4 a4 = *reinterpret_cast<const float4*>(av + j);
    s += wv.x * a4.x + wv.y * a4.y + wv.z * a4.z + wv.w * a4.w;
  }
  Wa[k * 8 + c] = s;
}

// ---------------- weight prep: pack W + Wa into B-fragment layout ----------
__global__ void k_prep(const float* __restrict__ W, const float* __restrict__ Wa,
                       uint4* __restrict__ WF) {
  int gid = blockIdx.x * 256 + threadIdx.x;  // 9*256 = 2304 = 36 frags * 64 lanes
  if (gid >= 2304) return;
  int lane = gid & 63, frag = gid >> 6;
  int t = frag / 9, ct = frag - t * 9;
  int quad = lane >> 4, r = lane & 15;
  int kbase = t * 32 + quad * 8;
  unsigned v[8];
  if (ct < 8) {
    int col = ct * 16 + r;
    #pragma unroll
    for (int j = 0; j < 8; ++j) v[j] = bfr(W[(size_t)(kbase + j) * 128 + col]);
  } else if (r < 8) {
    #pragma unroll
    for (int j = 0; j < 8; ++j) v[j] = bfr(Wa[(kbase + j) * 8 + r]);
  } else {
    #pragma unroll
    for (int j = 0; j < 8; ++j) v[j] = 0;
  }
  uint4 pk;
  pk.x = v[0] | (v[1] << 16);
  pk.y = v[2] | (v[3] << 16);
  pk.z = v[4] | (v[5] << 16);
  pk.w = v[6] | (v[7] << 16);
  WF[gid] = pk;
}

// ---------------- MFMA GEMM + attention logits ----------------
__global__ __launch_bounds__(256) void k_mm(
    const float* __restrict__ X, const uint4* __restrict__ WF,
    unsigned short* __restrict__ H, float* __restrict__ AL, int n) {
  __shared__ uint4 wf[2304];
  int tid = threadIdx.x;
  #pragma unroll
  for (int i = 0; i < 9; ++i) wf[i * 256 + tid] = WF[i * 256 + tid];
  __syncthreads();
  int lane = tid & 63, wid = tid >> 6;
  int quad = lane >> 4, r = lane & 15;
  int rowbase = blockIdx.x * 64 + wid * 16;
  int arow = rowbase + r;
  int arowc = arow < n ? arow : 0;
  const float* xp = X + (size_t)arowc * 128 + quad * 8;
  const bf16x8* wfs = (const bf16x8*)wf;

  f32x4 acc[9];
  #pragma unroll
  for (int ct = 0; ct < 9; ++ct) acc[ct] = 0;

  #pragma unroll
  for (int t = 0; t < 4; ++t) {
    float4 x0 = *reinterpret_cast<const float4*>(xp + t * 32);
    float4 x1 = *reinterpret_cast<const float4*>(xp + t * 32 + 4);
    bf16x8 a;
    a[0] = (short)bfr(x0.x); a[1] = (short)bfr(x0.y);
    a[2] = (short)bfr(x0.z); a[3] = (short)bfr(x0.w);
    a[4] = (short)bfr(x1.x); a[5] = (short)bfr(x1.y);
    a[6] = (short)bfr(x1.z); a[7] = (short)bfr(x1.w);
    #pragma unroll
    for (int ct = 0; ct < 9; ++ct)
      acc[ct] = __builtin_amdgcn_mfma_f32_16x16x32_bf16(
          a, wfs[(t * 9 + ct) * 64 + lane], acc[ct], 0, 0, 0);
  }

  int orow0 = rowbase + quad * 4;
  #pragma unroll
  for (int rr = 0; rr < 4; ++rr) {
    int orow = orow0 + rr;
    if (orow < n) {
      unsigned short* hp = H + (size_t)orow * 128 + r;
      #pragma unroll
      for (int ct = 0; ct < 8; ++ct) hp[ct * 16] = (unsigned short)bfr(acc[ct][rr]);
      if (r < 8) AL[(size_t)orow * 8 + r] = acc[8][rr];
    }
  }
}

// ---------------- per-dst softmax + aggregation ----------------
// One node per 16-lane group (4 nodes/wave, 16/block). No max shift (logits
// O(1); exp(e)/sum == exp(e-m)/sum). Stage (p,src) in group-private LDS,
// gather feature-parallel: lane owns one uint4 (8 bf16) of the H row.
template<bool ELU_OUT>
__global__ __launch_bounds__(256) void k_agg(
    const unsigned short* __restrict__ H, const float* __restrict__ AL,
    const int* __restrict__ offs, const int* __restrict__ csr,
    const float* __restrict__ bias, float* __restrict__ OUT, int n) {
  __shared__ int s_l[16][16];
  __shared__ float p_l[16][16][4];
  int tid = threadIdx.x;
  int lane = tid & 63;
  int wid = tid >> 6;
  int r = lane & 15;
  int gg = wid * 4 + (lane >> 4);     // group id within block (0..15)
  int node = blockIdx.x * 16 + gg;
  bool nvalid = node < n;
  int nodec = nvalid ? node : 0;
  int beg = offs[nodec];
  int end = nvalid ? offs[nodec + 1] : beg;
  float4 adv = *reinterpret_cast<const float4*>(AL + (size_t)nodec * 8 + 4);
  int hsel = r >> 2;
  const uint4* hb = reinterpret_cast<const uint4*>(H) + r;

  float z0 = 0.f, z1 = 0.f, z2 = 0.f, z3 = 0.f;
  float acc[8];
  #pragma unroll
  for (int k = 0; k < 8; ++k) acc[k] = 0.f;

  for (int cb = beg; cb < end; cb += 16) {
    int idx = cb + r;
    bool v = idx < end;
    int s = 0;
    float p0 = 0.f, p1 = 0.f, p2 = 0.f, p3 = 0.f;
    if (v) {
      s = csr[idx];
      float4 a = *reinterpret_cast<const float4*>(AL + (size_t)s * 8);
      p0 = __expf(lrelu(a.x + adv.x));
      p1 = __expf(lrelu(a.y + adv.y));
      p2 = __expf(lrelu(a.z + adv.z));
      p3 = __expf(lrelu(a.w + adv.w));
    }
    z0 += p0; z1 += p1; z2 += p2; z3 += p3;

    s_l[gg][r] = s;
    *reinterpret_cast<float4*>(&p_l[gg][r][0]) = make_float4(p0, p1, p2, p3);
    // wave-coherent LDS (group lives in one wave): no barrier needed

    int cnt = min(16, end - cb);
    int j = 0;
    for (; j + 2 <= cnt; j += 2) {
      int sA = s_l[gg][j], sB = s_l[gg][j + 1];
      float pA = p_l[gg][j][hsel], pB = p_l[gg][j + 1][hsel];
      uint4 uA = hb[(size_t)sA * 16];
      uint4 uB = hb[(size_t)sB * 16];
      acc[0] = fmaf(pA, blo(uA.x), acc[0]); acc[1] = fmaf(pA, bhi(uA.x), acc[1]);
      acc[2] = fmaf(pA, blo(uA.y), acc[2]); acc[3] = fmaf(pA, bhi(uA.y), acc[3]);
      acc[4] = fmaf(pA, blo(uA.z), acc[4]); acc[5] = fmaf(pA, bhi(uA.z), acc[5]);
      acc[6] = fmaf(pA, blo(uA.w), acc[6]); acc[7] = fmaf(pA, bhi(uA.w), acc[7]);
      acc[0] = fmaf(pB, blo(uB.x), acc[0]); acc[1] = fmaf(pB, bhi(uB.x), acc[1]);
      acc[2] = fmaf(pB, blo(uB.y), acc[2]); acc[3] = fmaf(pB, bhi(uB.y), acc[3]);
      acc[4] = fmaf(pB, blo(uB.z), acc[4]); acc[5] = fmaf(pB, bhi(uB.z), acc[5]);
      acc[6] = fmaf(pB, blo(uB.w), acc[6]); acc[7] = fmaf(pB, bhi(uB.w), acc[7]);
    }
    if (j < cnt) {
      int sA = s_l[gg][j];
      float pA = p_l[gg][j][hsel];
      uint4 uA = hb[(size_t)sA * 16];
      acc[0] = fmaf(pA, blo(uA.x), acc[0]); acc[1] = fmaf(pA, bhi(uA.x), acc[1]);
      acc[2] = fmaf(pA, blo(uA.y), acc[2]); acc[3] = fmaf(pA, bhi(uA.y), acc[3]);
      acc[4] = fmaf(pA, blo(uA.z), acc[4]); acc[5] = fmaf(pA, bhi(uA.z), acc[5]);
      acc[6] = fmaf(pA, blo(uA.w), acc[6]); acc[7] = fmaf(pA, bhi(uA.w), acc[7]);
    }
  }

  // z reduction within the 16-lane group
  #pragma unroll
  for (int off = 1; off < 16; off <<= 1) {
    z0 += __shfl_xor(z0, off);
    z1 += __shfl_xor(z1, off);
    z2 += __shfl_xor(z2, off);
    z3 += __shfl_xor(z3, off);
  }
  float zh = (hsel == 0) ? z0 : (hsel == 1) ? z1 : (hsel == 2) ? z2 : z3;
  float inv = 1.f / (zh + 1e-16f);
  int f0 = r * 8;
  float4 b0 = *reinterpret_cast<const float4*>(bias + f0);
  float4 b1 = *reinterpret_cast<const float4*>(bias + f0 + 4);
  float o[8];
  o[0] = acc[0] * inv + b0.x; o[1] = acc[1] * inv + b0.y;
  o[2] = acc[2] * inv + b0.z; o[3] = acc[3] * inv + b0.w;
  o[4] = acc[4] * inv + b1.x; o[5] = acc[5] * inv + b1.y;
  o[6] = acc[6] * inv + b1.z; o[7] = acc[7] * inv + b1.w;
  if (ELU_OUT) {
    #pragma unroll
    for (int k = 0; k < 8; ++k) o[k] = o[k] > 0.f ? o[k] : expm1f(o[k]);
  }
  if (nvalid) {
    float* op = OUT + (size_t)node * 128 + f0;
    *reinterpret_cast<float4*>(op) = make_float4(o[0], o[1], o[2], o[3]);
    *reinterpret_cast<float4*>(op + 4) = make_float4(o[4], o[5], o[6], o[7]);
  }
}

// ---------------- pooling (batch is sorted) ----------------
__global__ __launch_bounds__(256) void k_pool(
    const float* __restrict__ X, const int* __restrict__ batch,
    float* __restrict__ pooled, int* __restrict__ gcnt, int n) {
  int lane = threadIdx.x & 63;
  int w = blockIdx.x * 4 + (threadIdx.x >> 6);
  int a = w * 64;
  if (a >= n) return;
  int b = min(a + 64, n);
  float accA = 0.f, accB = 0.f;
  int gcur = batch[a];
  int cg = 0;
  int node = a;
  while (node < b) {
    if (node + 4 <= b && batch[node + 3] == gcur) {
      float sA0 = X[(size_t)(node + 0) * 128 + lane];
      float sB0 = X[(size_t)(node + 0) * 128 + lane + 64];
      float sA1 = X[(size_t)(node + 1) * 128 + lane];
      float sB1 = X[(size_t)(node + 1) * 128 + lane + 64];
      float sA2 = X[(size_t)(node + 2) * 128 + lane];
      float sB2 = X[(size_t)(node + 2) * 128 + lane + 64];
      float sA3 = X[(size_t)(node + 3) * 128 + lane];
      float sB3 = X[(size_t)(node + 3) * 128 + lane + 64];
      accA += (sA0 + sA1) + (sA2 + sA3);
      accB += (sB0 + sB1) + (sB2 + sB3);
      cg += 4; node += 4;
      continue;
    }
    int g = batch[node];
    if (g != gcur) {
      atomicAdd(&pooled[(size_t)gcur * 128 + lane], accA);
      atomicAdd(&pooled[(size_t)gcur * 128 + lane + 64], accB);
      if (lane == 0) atomicAdd(&gcnt[gcur], cg);
      accA = accB = 0.f; cg = 0; gcur = g;
    }
    accA += X[(size_t)node * 128 + lane];
    accB += X[(size_t)node * 128 + lane + 64];
    ++cg; ++node;
  }
  atomicAdd(&pooled[(size_t)gcur * 128 + lane], accA);
  atomicAdd(&pooled[(size_t)gcur * 128 + lane + 64], accB);
  if (lane == 0) atomicAdd(&gcnt[gcur], cg);
}

// ---------------- classifier head ----------------
__global__ void k_head(const float* __restrict__ pooled, const int* __restrict__ gcnt,
                       const float* __restrict__ Wl, const float* __restrict__ bl,
                       float* __restrict__ out) {
  int g = blockIdx.x;
  int lane = threadIdx.x;  // 64 threads
  float cnt = fmaxf((float)gcnt[g], 1.f);
  float pA = pooled[(size_t)g * 128 + lane] / cnt;
  float pB = pooled[(size_t)g * 128 + lane + 64] / cnt;
  float l[OUTC];
  #pragma unroll
  for (int o = 0; o < OUTC; ++o) {
    float s = pA * Wl[lane * OUTC + o] + pB * Wl[(lane + 64) * OUTC + o];
    #pragma unroll
    for (int off = 32; off; off >>= 1) s += __shfl_xor(s, off);
    l[o] = s + bl[o];
  }
  float mx = l[0];
  #pragma unroll
  for (int o = 1; o < OUTC; ++o) mx = fmaxf(mx, l[o]);
  float se = 0.f;
  #pragma unroll
  for (int o = 0; o < OUTC; ++o) { l[o] = __expf(l[o] - mx); se += l[o]; }
  if (lane == 0) {
    float inv = 1.f / se;
    #pragma unroll
    for (int o = 0; o < OUTC; ++o) out[g * OUTC + o] = l[o] * inv;
  }
}

extern "C" void kernel_launch(void* const* d_in, const int* in_sizes, int n_in,
                              void* d_out, int out_size, void* d_ws, size_t ws_size,
                              hipStream_t stream) {
  const float* x   = (const float*)d_in[0];
  const float* W1  = (const float*)d_in[1];
  const float* a1s = (const float*)d_in[2];
  const float* a1d = (const float*)d_in[3];
  const float* b1  = (const float*)d_in[4];
  const float* W2  = (const float*)d_in[5];
  const float* a2s = (const float*)d_in[6];
  const float* a2d = (const float*)d_in[7];
  const float* b2  = (const float*)d_in[8];
  const float* Wl  = (const float*)d_in[9];
  const float* bl  = (const float*)d_in[10];
  const int* ei    = (const int*)d_in[11];
  const int* batch = (const int*)d_in[12];
  const int N = in_sizes[12];
  const int E = in_sizes[11] / 2;
  const int G = out_size / OUTC;
  float* out = (float*)d_out;
  (void)n_in; (void)ws_size;

  const int tot = E + N;
  const int NB = (N + 255) / 256;  // dst buckets of 256

  char* w = (char*)d_ws;
  auto alloc = [&](size_t bytes) { char* p = w; w += (bytes + 255) & ~(size_t)255; return (void*)p; };
  unsigned short* H = (unsigned short*)alloc((size_t)N * FDIM * sizeof(unsigned short));
  float* ACT    = (float*)alloc((size_t)N * FDIM * sizeof(float));
  float* AL     = (float*)alloc((size_t)N * 8 * sizeof(float));
  uint4* WF1    = (uint4*)alloc(2304 * sizeof(uint4));
  uint4* WF2    = (uint4*)alloc(2304 * sizeof(uint4));
  float* Wa     = (float*)alloc(128 * 8 * sizeof(float));
  int*   offs   = (int*)alloc((size_t)(N + 1) * sizeof(int));
  int*   csr    = (int*)alloc((size_t)tot * sizeof(int));
  int2*  bbuf   = (int2*)alloc((size_t)tot * sizeof(int2));
  int*   bbase  = (int*)alloc((size_t)(NB + 1) * sizeof(int));
  int*   gbcur  = (int*)alloc(256 * sizeof(int));
  // zero-init region: gbc, gcnt, pooled contiguous -> one memset
  char* z0 = w;
  int*   gbc    = (int*)alloc(256 * sizeof(int));
  int*   gcnt   = (int*)alloc((size_t)G * sizeof(int));
  float* pooled = (float*)alloc((size_t)G * FDIM * sizeof(float));
  size_t zbytes = (size_t)(w - z0);
  hipMemsetAsync(z0, 0, zbytes, stream);

  // CSR build (bucketed)
  int ab4 = (tot + CHUNK - 1) / CHUNK;
  k_bhist<<<ab4, 256, 0, stream>>>(ei, gbc, E, N, NB);
  k_bscan<<<1, 256, 0, stream>>>(gbc, bbase, gbcur, NB);
  k_bin<<<ab4, 256, 0, stream>>>(ei, gbcur, bbuf, E, N);
  k_build<<<NB, 256, 0, stream>>>(bbuf, bbase, offs, csr, N, NB);

  // weight prep (independent of CSR)
  k_wa<<<8, 128, 0, stream>>>(W1, a1s, a1d, Wa);
  k_prep<<<9, 256, 0, stream>>>(W1, Wa, WF1);
  k_wa<<<8, 128, 0, stream>>>(W2, a2s, a2d, Wa);
  k_prep<<<9, 256, 0, stream>>>(W2, Wa, WF2);

  int gb = (N + 63) / 64;
  int ab = (N + 15) / 16;
  k_mm<<<gb, 256, 0, stream>>>(x, WF1, H, AL, N);
  k_agg<true><<<ab, 256, 0, stream>>>(H, AL, offs, csr, b1, ACT, N);
  k_mm<<<gb, 256, 0, stream>>>(ACT, WF2, H, AL, N);
  k_agg<false><<<ab, 256, 0, stream>>>(H, AL, offs, csr, b2, ACT, N);

  int pb = (N + 255) / 256;
  k_pool<<<pb, 256, 0, stream>>>(ACT, batch, pooled, gcnt, N);
  k_head<<<G, 64, 0, stream>>>(pooled, gcnt, Wl, bl, out);
}

// Round 7
// 243.749 us; speedup vs baseline: 1.2775x; 1.0369x over previous
//
#include <hip/hip_runtime.h>
#include <hip/hip_bf16.h>
#include <math.h>

#define HEADS 4
#define HID 32
#define FDIM 128   // HEADS*HID == IN
#define OUTC 10
#define NEG 0.2f

typedef __attribute__((ext_vector_type(4))) float f32x4;
typedef __attribute__((ext_vector_type(8))) short bf16x8;

static __device__ __forceinline__ float lrelu(float v) { return v > 0.f ? v : NEG * v; }

// round-to-nearest-even f32 -> bf16 (returns low 16 bits)
static __device__ __forceinline__ unsigned bfr(float f) {
  unsigned u = __float_as_uint(f);
  return (u + 0x7fffu + ((u >> 16) & 1u)) >> 16;
}
static __device__ __forceinline__ float blo(unsigned u) { return __uint_as_float(u << 16); }
static __device__ __forceinline__ float bhi(unsigned u) { return __uint_as_float(u & 0xffff0000u); }

// ================= bucketed CSR build =================
// Buckets of 256 consecutive dst ids. Each CSR region is written by exactly
// ONE workgroup (one XCD) -> cache lines fully packed before writeback.

#define CHUNK 4096  // edges per block in hist/bin passes

__global__ __launch_bounds__(256) void k_bhist(
    const int* __restrict__ ei, int* __restrict__ gbc, int E, int n, int nb) {
  __shared__ int h[256];
  h[threadIdx.x] = 0;
  __syncthreads();
  int base = blockIdx.x * CHUNK;
  int tot = E + n;
  #pragma unroll
  for (int r = 0; r < 16; ++r) {
    int e = base + r * 256 + threadIdx.x;
    if (e < tot) {
      int dst = (e < E) ? ei[E + e] : (e - E);
      atomicAdd(&h[dst >> 8], 1);
    }
  }
  __syncthreads();
  if (threadIdx.x < nb && h[threadIdx.x]) atomicAdd(&gbc[threadIdx.x], h[threadIdx.x]);
}

__global__ void k_bscan(const int* __restrict__ gbc, int* __restrict__ bbase,
                        int* __restrict__ gbcur, int nb) {
  __shared__ int sh[256];
  int v = (threadIdx.x < nb) ? gbc[threadIdx.x] : 0;
  sh[threadIdx.x] = v;
  __syncthreads();
  #pragma unroll
  for (int off = 1; off < 256; off <<= 1) {
    int t = (threadIdx.x >= off) ? sh[threadIdx.x - off] : 0;
    __syncthreads();
    sh[threadIdx.x] += t;
    __syncthreads();
  }
  int excl = sh[threadIdx.x] - v;
  if (threadIdx.x <= nb) bbase[threadIdx.x] = excl;
  if (threadIdx.x < nb) gbcur[threadIdx.x] = excl;
}

__global__ __launch_bounds__(256) void k_bin(
    const int* __restrict__ ei, int* __restrict__ gbcur,
    int2* __restrict__ bbuf, int E, int n) {
  __shared__ int h[256];
  __shared__ int cur[256];
  h[threadIdx.x] = 0;
  __syncthreads();
  int base = blockIdx.x * CHUNK;
  int tot = E + n;
  #pragma unroll
  for (int r = 0; r < 16; ++r) {
    int e = base + r * 256 + threadIdx.x;
    if (e < tot) {
      int dst = (e < E) ? ei[E + e] : (e - E);
      atomicAdd(&h[dst >> 8], 1);
    }
  }
  __syncthreads();
  if (h[threadIdx.x]) cur[threadIdx.x] = atomicAdd(&gbcur[threadIdx.x], h[threadIdx.x]);
  __syncthreads();
  #pragma unroll
  for (int r = 0; r < 16; ++r) {
    int e = base + r * 256 + threadIdx.x;
    if (e < tot) {
      int src = (e < E) ? ei[e] : (e - E);
      int dst = (e < E) ? ei[E + e] : (e - E);
      int pos = atomicAdd(&cur[dst >> 8], 1);
      bbuf[pos] = make_int2(src, dst);
    }
  }
}

__global__ __launch_bounds__(256) void k_build(
    const int2* __restrict__ bbuf, const int* __restrict__ bbase,
    int* __restrict__ offs, int* __restrict__ csr, int n, int nb) {
  __shared__ int deg[256];
  __shared__ int sc[256];
  __shared__ int cur[256];
  int b = blockIdx.x;
  int ebeg = bbase[b], eend = bbase[b + 1];
  deg[threadIdx.x] = 0;
  __syncthreads();
  for (int i = ebeg + threadIdx.x; i < eend; i += 256)
    atomicAdd(&deg[bbuf[i].y & 255], 1);
  __syncthreads();
  int v = deg[threadIdx.x];
  sc[threadIdx.x] = v;
  __syncthreads();
  #pragma unroll
  for (int off = 1; off < 256; off <<= 1) {
    int t = (threadIdx.x >= off) ? sc[threadIdx.x - off] : 0;
    __syncthreads();
    sc[threadIdx.x] += t;
    __syncthreads();
  }
  int excl = sc[threadIdx.x] - v;
  int dst0 = b * 256 + threadIdx.x;
  if (dst0 < n) offs[dst0] = ebeg + excl;
  if (b == 0 && threadIdx.x == 0) offs[n] = bbase[nb];
  cur[threadIdx.x] = ebeg + excl;
  __syncthreads();
  for (int i = ebeg + threadIdx.x; i < eend; i += 256) {
    int2 sd = bbuf[i];
    int pos = atomicAdd(&cur[sd.y & 255], 1);
    csr[pos] = sd.x;
  }
}

// ---------------- Wa = W @ [a_src; a_dst]^T, both layers ----------------
__global__ void k_wa(const float* __restrict__ W1, const float* __restrict__ W2,
                     const float* __restrict__ a1s, const float* __restrict__ a1d,
                     const float* __restrict__ a2s, const float* __restrict__ a2d,
                     float* __restrict__ Wa) {
  int layer = blockIdx.y;
  const float* W = layer ? W2 : W1;
  int c = blockIdx.x;       // 0..7: 0-3 src heads, 4-7 dst heads
  int k = threadIdx.x;      // 0..127
  int h = c & 3;
  const float* av = (c < 4 ? (layer ? a2s : a1s) : (layer ? a2d : a1d)) + h * 32;
  const float* wr = W + (size_t)k * 128 + h * 32;
  float s = 0.f;
  #pragma unroll
  for (int j = 0; j < 32; j += 4) {
    float4 wv = *reinterpret_cast<const float4*>(wr + j);
    float4 a4 = *reinterpret_cast<const float4*>(av + j);
    s += wv.x * a4.x + wv.y * a4.y + wv.z * a4.z + wv.w * a4.w;
  }
  Wa[layer * 1024 + k * 8 + c] = s;
}

// ---------------- weight prep: pack W + Wa into B-fragment layout ----------
__global__ void k_prep(const float* __restrict__ W1, const float* __restrict__ W2,
                       const float* __restrict__ Wa, uint4* __restrict__ WF) {
  int layer = blockIdx.y;
  const float* W = layer ? W2 : W1;
  const float* wa = Wa + layer * 1024;
  int gid = blockIdx.x * 256 + threadIdx.x;  // 9*256 = 2304 = 36 frags * 64 lanes
  if (gid >= 2304) return;
  int lane = gid & 63, frag = gid >> 6;
  int t = frag / 9, ct = frag - t * 9;
  int quad = lane >> 4, r = lane & 15;
  int kbase = t * 32 + quad * 8;
  unsigned v[8];
  if (ct < 8) {
    int col = ct * 16 + r;
    #pragma unroll
    for (int j = 0; j < 8; ++j) v[j] = bfr(W[(size_t)(kbase + j) * 128 + col]);
  } else if (r < 8) {
    #pragma unroll
    for (int j = 0; j < 8; ++j) v[j] = bfr(wa[(kbase + j) * 8 + r]);
  } else {
    #pragma unroll
    for (int j = 0; j < 8; ++j) v[j] = 0;
  }
  uint4 pk;
  pk.x = v[0] | (v[1] << 16);
  pk.y = v[2] | (v[3] << 16);
  pk.z = v[4] | (v[5] << 16);
  pk.w = v[6] | (v[7] << 16);
  WF[layer * 2304 + gid] = pk;
}

// ---------------- MFMA GEMM + attention logits ----------------
__global__ __launch_bounds__(256) void k_mm(
    const float* __restrict__ X, const uint4* __restrict__ WF,
    unsigned short* __restrict__ H, float* __restrict__ AL, int n) {
  __shared__ uint4 wf[2304];
  int tid = threadIdx.x;
  #pragma unroll
  for (int i = 0; i < 9; ++i) wf[i * 256 + tid] = WF[i * 256 + tid];
  __syncthreads();
  int lane = tid & 63, wid = tid >> 6;
  int quad = lane >> 4, r = lane & 15;
  int rowbase = blockIdx.x * 64 + wid * 16;
  int arow = rowbase + r;
  int arowc = arow < n ? arow : 0;
  const float* xp = X + (size_t)arowc * 128 + quad * 8;
  const bf16x8* wfs = (const bf16x8*)wf;

  f32x4 acc[9];
  #pragma unroll
  for (int ct = 0; ct < 9; ++ct) acc[ct] = 0;

  #pragma unroll
  for (int t = 0; t < 4; ++t) {
    float4 x0 = *reinterpret_cast<const float4*>(xp + t * 32);
    float4 x1 = *reinterpret_cast<const float4*>(xp + t * 32 + 4);
    bf16x8 a;
    a[0] = (short)bfr(x0.x); a[1] = (short)bfr(x0.y);
    a[2] = (short)bfr(x0.z); a[3] = (short)bfr(x0.w);
    a[4] = (short)bfr(x1.x); a[5] = (short)bfr(x1.y);
    a[6] = (short)bfr(x1.z); a[7] = (short)bfr(x1.w);
    #pragma unroll
    for (int ct = 0; ct < 9; ++ct)
      acc[ct] = __builtin_amdgcn_mfma_f32_16x16x32_bf16(
          a, wfs[(t * 9 + ct) * 64 + lane], acc[ct], 0, 0, 0);
  }

  int orow0 = rowbase + quad * 4;
  #pragma unroll
  for (int rr = 0; rr < 4; ++rr) {
    int orow = orow0 + rr;
    if (orow < n) {
      unsigned short* hp = H + (size_t)orow * 128 + r;
      #pragma unroll
      for (int ct = 0; ct < 8; ++ct) hp[ct * 16] = (unsigned short)bfr(acc[ct][rr]);
      if (r < 8) AL[(size_t)orow * 8 + r] = acc[8][rr];
    }
  }
}

// ---------------- per-dst softmax + aggregation ----------------
// One node per 16-lane group (4 nodes/wave, 16/block). No max shift (logits
// O(1); exp(e)/sum == exp(e-m)/sum). Gather loop unrolled x4 -> 4 x 1KB
// wave-gathers in flight. POOL=true (layer 2): block-local segmented
// reduction by graph id -> ~136 atomics/block into L2-hot pooled[].
template<bool ELU_OUT, bool POOL>
__global__ __launch_bounds__(256) void k_agg(
    const unsigned short* __restrict__ H, const float* __restrict__ AL,
    const int* __restrict__ offs, const int* __restrict__ csr,
    const float* __restrict__ bias, float* __restrict__ OUT,
    const int* __restrict__ batch, float* __restrict__ pooled,
    int* __restrict__ gcnt, int n) {
  __shared__ int s_l[16][16];
  __shared__ float p_l[16][16][4];
  __shared__ float o_l[POOL ? 16 : 1][POOL ? 132 : 1];
  __shared__ int g_l[16];
  int tid = threadIdx.x;
  int lane = tid & 63;
  int wid = tid >> 6;
  int r = lane & 15;
  int gg = wid * 4 + (lane >> 4);     // group id within block (0..15)
  int node = blockIdx.x * 16 + gg;
  bool nvalid = node < n;
  int nodec = nvalid ? node : 0;
  int beg = offs[nodec];
  int end = nvalid ? offs[nodec + 1] : beg;
  float4 adv = *reinterpret_cast<const float4*>(AL + (size_t)nodec * 8 + 4);
  int hsel = r >> 2;
  const uint4* hb = reinterpret_cast<const uint4*>(H) + r;

  if (POOL && r == 0) g_l[gg] = nvalid ? batch[node] : -1;

  float z0 = 0.f, z1 = 0.f, z2 = 0.f, z3 = 0.f;
  float acc[8];
  #pragma unroll
  for (int k = 0; k < 8; ++k) acc[k] = 0.f;

  for (int cb = beg; cb < end; cb += 16) {
    int idx = cb + r;
    bool v = idx < end;
    int s = 0;
    float p0 = 0.f, p1 = 0.f, p2 = 0.f, p3 = 0.f;
    if (v) {
      s = csr[idx];
      float4 a = *reinterpret_cast<const float4*>(AL + (size_t)s * 8);
      p0 = __expf(lrelu(a.x + adv.x));
      p1 = __expf(lrelu(a.y + adv.y));
      p2 = __expf(lrelu(a.z + adv.z));
      p3 = __expf(lrelu(a.w + adv.w));
    }
    z0 += p0; z1 += p1; z2 += p2; z3 += p3;

    s_l[gg][r] = s;
    *reinterpret_cast<float4*>(&p_l[gg][r][0]) = make_float4(p0, p1, p2, p3);
    // wave-coherent LDS (group lives in one wave): no barrier needed

    int cnt = min(16, end - cb);
    for (int j0 = 0; j0 < cnt; j0 += 4) {
      int j1 = j0 + 1, j2 = j0 + 2, j3 = j0 + 3;
      bool v1 = j1 < cnt, v2 = j2 < cnt, v3 = j3 < cnt;
      int jB = v1 ? j1 : j0, jC = v2 ? j2 : j0, jD = v3 ? j3 : j0;
      int sA = s_l[gg][j0], sB = s_l[gg][jB], sC = s_l[gg][jC], sD = s_l[gg][jD];
      float pA = p_l[gg][j0][hsel];
      float pB = v1 ? p_l[gg][jB][hsel] : 0.f;
      float pC = v2 ? p_l[gg][jC][hsel] : 0.f;
      float pD = v3 ? p_l[gg][jD][hsel] : 0.f;
      uint4 uA = hb[(size_t)sA * 16];
      uint4 uB = hb[(size_t)sB * 16];
      uint4 uC = hb[(size_t)sC * 16];
      uint4 uD = hb[(size_t)sD * 16];
      acc[0] = fmaf(pA, blo(uA.x), acc[0]); acc[1] = fmaf(pA, bhi(uA.x), acc[1]);
      acc[2] = fmaf(pA, blo(uA.y), acc[2]); acc[3] = fmaf(pA, bhi(uA.y), acc[3]);
      acc[4] = fmaf(pA, blo(uA.z), acc[4]); acc[5] = fmaf(pA, bhi(uA.z), acc[5]);
      acc[6] = fmaf(pA, blo(uA.w), acc[6]); acc[7] = fmaf(pA, bhi(uA.w), acc[7]);
      acc[0] = fmaf(pB, blo(uB.x), acc[0]); acc[1] = fmaf(pB, bhi(uB.x), acc[1]);
      acc[2] = fmaf(pB, blo(uB.y), acc[2]); acc[3] = fmaf(pB, bhi(uB.y), acc[3]);
      acc[4] = fmaf(pB, blo(uB.z), acc[4]); acc[5] = fmaf(pB, bhi(uB.z), acc[5]);
      acc[6] = fmaf(pB, blo(uB.w), acc[6]); acc[7] = fmaf(pB, bhi(uB.w), acc[7]);
      acc[0] = fmaf(pC, blo(uC.x), acc[0]); acc[1] = fmaf(pC, bhi(uC.x), acc[1]);
      acc[2] = fmaf(pC, blo(uC.y), acc[2]); acc[3] = fmaf(pC, bhi(uC.y), acc[3]);
      acc[4] = fmaf(pC, blo(uC.z), acc[4]); acc[5] = fmaf(pC, bhi(uC.z), acc[5]);
      acc[6] = fmaf(pC, blo(uC.w), acc[6]); acc[7] = fmaf(pC, bhi(uC.w), acc[7]);
      acc[0] = fmaf(pD, blo(uD.x), acc[0]); acc[1] = fmaf(pD, bhi(uD.x), acc[1]);
      acc[2] = fmaf(pD, blo(uD.y), acc[2]); acc[3] = fmaf(pD, bhi(uD.y), acc[3]);
      acc[4] = fmaf(pD, blo(uD.z), acc[4]); acc[5] = fmaf(pD, bhi(uD.z), acc[5]);
      acc[6] = fmaf(pD, blo(uD.w), acc[6]); acc[7] = fmaf(pD, bhi(uD.w), acc[7]);
    }
  }

  // z reduction within the 16-lane group
  #pragma unroll
  for (int off = 1; off < 16; off <<= 1) {
    z0 += __shfl_xor(z0, off);
    z1 += __shfl_xor(z1, off);
    z2 += __shfl_xor(z2, off);
    z3 += __shfl_xor(z3, off);
  }
  float zh = (hsel == 0) ? z0 : (hsel == 1) ? z1 : (hsel == 2) ? z2 : z3;
  float inv = 1.f / (zh + 1e-16f);
  int f0 = r * 8;
  float4 b0 = *reinterpret_cast<const float4*>(bias + f0);
  float4 b1 = *reinterpret_cast<const float4*>(bias + f0 + 4);
  float o[8];
  o[0] = acc[0] * inv + b0.x; o[1] = acc[1] * inv + b0.y;
  o[2] = acc[2] * inv + b0.z; o[3] = acc[3] * inv + b0.w;
  o[4] = acc[4] * inv + b1.x; o[5] = acc[5] * inv + b1.y;
  o[6] = acc[6] * inv + b1.z; o[7] = acc[7] * inv + b1.w;
  if (ELU_OUT) {
    #pragma unroll
    for (int k = 0; k < 8; ++k) o[k] = o[k] > 0.f ? o[k] : expm1f(o[k]);
  }

  if (!POOL) {
    if (nvalid) {
      float* op = OUT + (size_t)node * 128 + f0;
      *reinterpret_cast<float4*>(op) = make_float4(o[0], o[1], o[2], o[3]);
      *reinterpret_cast<float4*>(op + 4) = make_float4(o[4], o[5], o[6], o[7]);
    }
  } else {
    *reinterpret_cast<float4*>(&o_l[gg][f0]) = make_float4(o[0], o[1], o[2], o[3]);
    *reinterpret_cast<float4*>(&o_l[gg][f0 + 4]) = make_float4(o[4], o[5], o[6], o[7]);
    __syncthreads();
    if (tid < 128) {
      int f = tid;
      float accp = 0.f; int cur = -1;
      #pragma unroll
      for (int i = 0; i < 16; ++i) {
        int g = g_l[i];
        if (g != cur) {
          if (cur >= 0) atomicAdd(&pooled[(size_t)cur * 128 + f], accp);
          cur = g; accp = 0.f;
        }
        if (g >= 0) accp += o_l[i][f];
      }
      if (cur >= 0) atomicAdd(&pooled[(size_t)cur * 128 + f], accp);
    } else if (tid == 128) {
      int cur = -1, c = 0;
      #pragma unroll
      for (int i = 0; i < 16; ++i) {
        int g = g_l[i];
        if (g != cur) { if (cur >= 0) atomicAdd(&gcnt[cur], c); cur = g; c = 0; }
        if (g >= 0) ++c;
      }
      if (cur >= 0) atomicAdd(&gcnt[cur], c);
    }
  }
}

// ---------------- classifier head ----------------
__global__ void k_head(const float* __restrict__ pooled, const int* __restrict__ gcnt,
                       const float* __restrict__ Wl, const float* __restrict__ bl,
                       float* __restrict__ out) {
  int g = blockIdx.x;
  int lane = threadIdx.x;  // 64 threads
  float cnt = fmaxf((float)gcnt[g], 1.f);
  float pA = pooled[(size_t)g * 128 + lane] / cnt;
  float pB = pooled[(size_t)g * 128 + lane + 64] / cnt;
  float l[OUTC];
  #pragma unroll
  for (int o = 0; o < OUTC; ++o) {
    float s = pA * Wl[lane * OUTC + o] + pB * Wl[(lane + 64) * OUTC + o];
    #pragma unroll
    for (int off = 32; off; off >>= 1) s += __shfl_xor(s, off);
    l[o] = s + bl[o];
  }
  float mx = l[0];
  #pragma unroll
  for (int o = 1; o < OUTC; ++o) mx = fmaxf(mx, l[o]);
  float se = 0.f;
  #pragma unroll
  for (int o = 0; o < OUTC; ++o) { l[o] = __expf(l[o] - mx); se += l[o]; }
  if (lane == 0) {
    float inv = 1.f / se;
    #pragma unroll
    for (int o = 0; o < OUTC; ++o) out[g * OUTC + o] = l[o] * inv;
  }
}

extern "C" void kernel_launch(void* const* d_in, const int* in_sizes, int n_in,
                              void* d_out, int out_size, void* d_ws, size_t ws_size,
                              hipStream_t stream) {
  const float* x   = (const float*)d_in[0];
  const float* W1  = (const float*)d_in[1];
  const float* a1s = (const float*)d_in[2];
  const float* a1d = (const float*)d_in[3];
  const float* b1  = (const float*)d_in[4];
  const float* W2  = (const float*)d_in[5];
  const float* a2s = (const float*)d_in[6];
  const float* a2d = (const float*)d_in[7];
  const float* b2  = (const float*)d_in[8];
  const float* Wl  = (const float*)d_in[9];
  const float* bl  = (const float*)d_in[10];
  const int* ei    = (const int*)d_in[11];
  const int* batch = (const int*)d_in[12];
  const int N = in_sizes[12];
  const int E = in_sizes[11] / 2;
  const int G = out_size / OUTC;
  float* out = (float*)d_out;
  (void)n_in; (void)ws_size;

  const int tot = E + N;
  const int NB = (N + 255) / 256;  // dst buckets of 256

  char* w = (char*)d_ws;
  auto alloc = [&](size_t bytes) { char* p = w; w += (bytes + 255) & ~(size_t)255; return (void*)p; };
  unsigned short* H = (unsigned short*)alloc((size_t)N * FDIM * sizeof(unsigned short));
  float* ACT    = (float*)alloc((size_t)N * FDIM * sizeof(float));
  float* AL     = (float*)alloc((size_t)N * 8 * sizeof(float));
  uint4* WF     = (uint4*)alloc(2 * 2304 * sizeof(uint4));
  float* Wa     = (float*)alloc(2 * 1024 * sizeof(float));
  int*   offs   = (int*)alloc((size_t)(N + 1) * sizeof(int));
  int*   csr    = (int*)alloc((size_t)tot * sizeof(int));
  int2*  bbuf   = (int2*)alloc((size_t)tot * sizeof(int2));
  int*   bbase  = (int*)alloc((size_t)(NB + 1) * sizeof(int));
  int*   gbcur  = (int*)alloc(256 * sizeof(int));
  // zero-init region: gbc, gcnt, pooled contiguous -> one memset
  char* z0 = w;
  int*   gbc    = (int*)alloc(256 * sizeof(int));
  int*   gcnt   = (int*)alloc((size_t)G * sizeof(int));
  float* pooled = (float*)alloc((size_t)G * FDIM * sizeof(float));
  size_t zbytes = (size_t)(w - z0);
  hipMemsetAsync(z0, 0, zbytes, stream);

  // CSR build (bucketed)
  int ab4 = (tot + CHUNK - 1) / CHUNK;
  k_bhist<<<ab4, 256, 0, stream>>>(ei, gbc, E, N, NB);
  k_bscan<<<1, 256, 0, stream>>>(gbc, bbase, gbcur, NB);
  k_bin<<<ab4, 256, 0, stream>>>(ei, gbcur, bbuf, E, N);
  k_build<<<NB, 256, 0, stream>>>(bbuf, bbase, offs, csr, N, NB);

  // weight prep (both layers, independent of CSR)
  k_wa<<<dim3(8, 2), 128, 0, stream>>>(W1, W2, a1s, a1d, a2s, a2d, Wa);
  k_prep<<<dim3(9, 2), 256, 0, stream>>>(W1, W2, Wa, WF);

  int gb = (N + 63) / 64;
  int ab = (N + 15) / 16;
  k_mm<<<gb, 256, 0, stream>>>(x, WF, H, AL, N);
  k_agg<true, false><<<ab, 256, 0, stream>>>(H, AL, offs, csr, b1, ACT, batch, pooled, gcnt, N);
  k_mm<<<gb, 256, 0, stream>>>(ACT, WF + 2304, H, AL, N);
  k_agg<false, true><<<ab, 256, 0, stream>>>(H, AL, offs, csr, b2, ACT, batch, pooled, gcnt, N);

  k_head<<<G, 64, 0, stream>>>(pooled, gcnt, Wl, bl, out);
}